// Round 10
// baseline (168.778 us; speedup 1.0000x reference)
//
#include <hip/hip_runtime.h>
#include <hip/hip_bf16.h>

#define N_NODES 50000
#define N_EDGES 400000
#define IN_DIM 128
#define HID 64
#define HEADS 4
#define L1_OUT (HEADS * HID)   // 256
#define OUT_DIM 64
#define NEG_SLOPE 0.2f
#define SCAN_B 256
#define HIST_B 1563            // ceil(400000/256)

typedef short bf16x8 __attribute__((ext_vector_type(8)));
typedef float f32x4 __attribute__((ext_vector_type(4)));

__device__ __forceinline__ float leaky(float x) { return x > 0.f ? x : NEG_SLOPE * x; }

// RNE float->bf16 bits, bf16 bits->float
__device__ __forceinline__ unsigned short bfh(float x) {
    unsigned u = __float_as_uint(x);
    return (unsigned short)((u + 0x7fffu + ((u >> 16) & 1u)) >> 16);
}
__device__ __forceinline__ float fb(unsigned short h) {
    return __uint_as_float(((unsigned)h) << 16);
}

// LDS A-frag slot swizzle (16B-slot index u): spreads kstep/g into the bank bits.
__device__ __forceinline__ int swzA(int u) {
    return u ^ (((u >> 6) & 7) ^ (((u >> 4) & 3) << 1));
}

// 16-lane-group softmax: edge jj's score sc -> alpha (within group of 16 lanes)
__device__ __forceinline__ float alpha16(float sc, int deg, int jj) {
    float m = sc;
    m = fmaxf(m, __shfl_xor(m, 1, 64));
    m = fmaxf(m, __shfl_xor(m, 2, 64));
    m = fmaxf(m, __shfl_xor(m, 4, 64));
    m = fmaxf(m, __shfl_xor(m, 8, 64));
    float ex = (jj < deg) ? __expf(sc - m) : 0.f;
    float ss = ex;
    ss += __shfl_xor(ss, 1, 64);
    ss += __shfl_xor(ss, 2, 64);
    ss += __shfl_xor(ss, 4, 64);
    ss += __shfl_xor(ss, 8, 64);
    return ex / ss;
}

#define FMA4(A, wv, g) { A.x += wv * fb(g.x); A.y += wv * fb(g.y); A.z += wv * fb(g.z); A.w += wv * fb(g.w); }

// fast-path aggregation (deg<=16): alpha/s_reg distributed over 16-lane groups; unroll 4
__device__ __forceinline__ float4 aggregate_fast(int deg, int s_reg, float alpha,
                                                 const ushort4* __restrict__ f4, int lane) {
    int hb = lane & 48;
    float4 A0{0,0,0,0}, A1{0,0,0,0}, A2{0,0,0,0}, A3{0,0,0,0};
    int j = 0;
    for (; j + 3 < deg; j += 4) {
        int t0 = __shfl(s_reg, j),     t1 = __shfl(s_reg, j + 1);
        int t2 = __shfl(s_reg, j + 2), t3 = __shfl(s_reg, j + 3);
        float w0 = __shfl(alpha, hb + j),     w1 = __shfl(alpha, hb + j + 1);
        float w2 = __shfl(alpha, hb + j + 2), w3 = __shfl(alpha, hb + j + 3);
        ushort4 g0 = f4[(size_t)t0 * 64 + lane];
        ushort4 g1 = f4[(size_t)t1 * 64 + lane];
        ushort4 g2 = f4[(size_t)t2 * 64 + lane];
        ushort4 g3 = f4[(size_t)t3 * 64 + lane];
        FMA4(A0, w0, g0); FMA4(A1, w1, g1); FMA4(A2, w2, g2); FMA4(A3, w3, g3);
    }
    for (; j < deg; ++j) {
        int t0 = __shfl(s_reg, j);
        float w0 = __shfl(alpha, hb + j);
        ushort4 g0 = f4[(size_t)t0 * 64 + lane];
        FMA4(A0, w0, g0);
    }
    float4 r;
    r.x = A0.x + A1.x + A2.x + A3.x;
    r.y = A0.y + A1.y + A2.y + A3.y;
    r.z = A0.z + A1.z + A2.z + A3.z;
    r.w = A0.w + A1.w + A2.w + A3.w;
    return r;
}

// rare fallback (deg > 16)
__device__ __forceinline__ float4 aggregate_slow(int d, int base, int deg,
                                                 const int* __restrict__ perm_src,
                                                 const float* __restrict__ el1,
                                                 const float* __restrict__ er1,
                                                 const ushort4* __restrict__ f4, int lane) {
    float mh0, mh1, mh2, mh3, iv0, iv1, iv2, iv3;
#pragma unroll
    for (int h = 0; h < 4; ++h) {
        float er_dh = er1[d * HEADS + h];
        float m = -1e30f;
        for (int j = lane; j < deg; j += 64)
            m = fmaxf(m, leaky(el1[perm_src[base + j] * HEADS + h] + er_dh));
#pragma unroll
        for (int off = 1; off < 64; off <<= 1) m = fmaxf(m, __shfl_xor(m, off, 64));
        float ss = 0.f;
        for (int j = lane; j < deg; j += 64)
            ss += __expf(leaky(el1[perm_src[base + j] * HEADS + h] + er_dh) - m);
#pragma unroll
        for (int off = 1; off < 64; off <<= 1) ss += __shfl_xor(ss, off, 64);
        float iv = 1.f / ss;
        if (h == 0) { mh0 = m; iv0 = iv; }
        else if (h == 1) { mh1 = m; iv1 = iv; }
        else if (h == 2) { mh2 = m; iv2 = iv; }
        else { mh3 = m; iv3 = iv; }
    }
    int hh = lane >> 4;
    float m_s = hh == 0 ? mh0 : hh == 1 ? mh1 : hh == 2 ? mh2 : mh3;
    float iv_s = hh == 0 ? iv0 : hh == 1 ? iv1 : hh == 2 ? iv2 : iv3;
    float er_s = er1[d * HEADS + hh];
    float4 acc = {0.f, 0.f, 0.f, 0.f};
    for (int j = 0; j < deg; ++j) {
        int s = perm_src[base + j];
        float a = __expf(leaky(el1[s * HEADS + hh] + er_s) - m_s) * iv_s;
        ushort4 f0 = f4[(size_t)s * 64 + lane];
        FMA4(acc, a, f0);
    }
    return acc;
}

// ---------------- CSR hist + W fragment prep (merged) ----------------
__global__ void hist_wprep_kernel(const int* __restrict__ dst, int* __restrict__ cnt,
                                  const float* __restrict__ W1, const float* __restrict__ W2,
                                  unsigned short* __restrict__ W1fh, unsigned short* __restrict__ W1fl,
                                  unsigned short* __restrict__ W2fh, unsigned short* __restrict__ W2fl) {
    int bid = blockIdx.x;
    if (bid < HIST_B) {
        int e = bid * 256 + threadIdx.x;
        if (e < N_EDGES) atomicAdd(&cnt[dst[e]], 1);
        return;
    }
    int s = (bid - HIST_B) * 256 + threadIdx.x;
    if (s < 4096) {
        int lane = s & 63, ks = (s >> 6) & 3, ntile = s >> 8;
        int n = ntile * 16 + (lane & 15);
        int kb = ks * 32 + (lane >> 4) * 8;
#pragma unroll
        for (int j = 0; j < 8; ++j) {
            float w = W1[(kb + j) * L1_OUT + n];
            unsigned short h = bfh(w);
            W1fh[s * 8 + j] = h;
            W1fl[s * 8 + j] = bfh(w - fb(h));
        }
    } else if (s < 6144) {
        int s2 = s - 4096;
        int lane = s2 & 63, ks = (s2 >> 6) & 7, ntile = s2 >> 9;
        int n = ntile * 16 + (lane & 15);
        int kb = ks * 32 + (lane >> 4) * 8;
#pragma unroll
        for (int j = 0; j < 8; ++j) {
            float w = W2[(kb + j) * OUT_DIM + n];
            unsigned short h = bfh(w);
            W2fh[s2 * 8 + j] = h;
            W2fl[s2 * 8 + j] = bfh(w - fb(h));
        }
    }
}

__global__ void scanA_kernel(const int* __restrict__ cnt, int* __restrict__ texcl,
                             int* __restrict__ bsum) {
    __shared__ int sh[SCAN_B];
    int tid = threadIdx.x;
    int i = blockIdx.x * SCAN_B + tid;
    int v = (i < N_NODES) ? cnt[i] : 0;
    sh[tid] = v;
    __syncthreads();
    for (int off = 1; off < SCAN_B; off <<= 1) {
        int t = (tid >= off) ? sh[tid - off] : 0;
        __syncthreads();
        sh[tid] += t;
        __syncthreads();
    }
    if (i < N_NODES) texcl[i] = sh[tid] - v;
    if (tid == SCAN_B - 1) bsum[blockIdx.x] = sh[tid];
}

__global__ void scanB_kernel(const int* __restrict__ bsum, int* __restrict__ bexcl, int nb) {
    __shared__ int sh[SCAN_B];
    int tid = threadIdx.x;
    int v = (tid < nb) ? bsum[tid] : 0;
    sh[tid] = v;
    __syncthreads();
    for (int off = 1; off < SCAN_B; off <<= 1) {
        int t = (tid >= off) ? sh[tid - off] : 0;
        __syncthreads();
        sh[tid] += t;
        __syncthreads();
    }
    if (tid < nb) bexcl[tid] = sh[tid] - v;
}

__global__ void scanC_kernel(const int* __restrict__ texcl, const int* __restrict__ bexcl,
                             int* __restrict__ row) {
    int i = blockIdx.x * blockDim.x + threadIdx.x;
    if (i < N_NODES) row[i] = texcl[i] + bexcl[i >> 8];
    if (blockIdx.x == 0 && threadIdx.x == 0) row[N_NODES] = N_EDGES;
}

__global__ void fill_kernel(const int* __restrict__ src, const int* __restrict__ dst,
                            const int* __restrict__ row, int* __restrict__ fc,
                            int* __restrict__ perm_src) {
    int e = blockIdx.x * blockDim.x + threadIdx.x;
    if (e >= N_EDGES) return;
    int d = dst[e];
    int p = row[d] + atomicAdd(&fc[d], 1);
    perm_src[p] = src[e];
}

// ---------------- gemm1 (MFMA): feat1b = bf16(X @ W1) + fused el1/er1 ----------------
__global__ __launch_bounds__(512) void gemm1_kernel(const float* __restrict__ X,
                                                    const unsigned short* __restrict__ W1fh,
                                                    const unsigned short* __restrict__ W1fl,
                                                    const float* __restrict__ al1,
                                                    const float* __restrict__ ar1,
                                                    unsigned short* __restrict__ feat1b,
                                                    float* __restrict__ el1,
                                                    float* __restrict__ er1) {
    __shared__ unsigned short Ah[4 * 4 * 64 * 8];   // [mfrag][kstep][lane][j]
    __shared__ unsigned short Al[4 * 4 * 64 * 8];
    int t = threadIdx.x;
    int m0 = blockIdx.x * 64;

    {
        int m = t >> 3;
        int k0 = (t & 7) * 16;
        int mfrag = m >> 4, mrow = m & 15;
        bool valid = (m0 + m) < N_NODES;
        const float4* xr = (const float4*)&X[(size_t)(m0 + m) * IN_DIM];
#pragma unroll
        for (int g = 0; g < 4; ++g) {
            int k = k0 + g * 4;
            float4 v = valid ? xr[k >> 2] : float4{0.f, 0.f, 0.f, 0.f};
            int kstep = k >> 5, kk = k & 31;
            int lane = mrow + 16 * (kk >> 3);
            int j0 = kk & 7;
            int base = ((mfrag * 4 + kstep) * 64 + lane) * 8 + j0;
            unsigned short h0 = bfh(v.x), h1 = bfh(v.y), h2 = bfh(v.z), h3 = bfh(v.w);
            *(ushort4*)&Ah[base] = make_ushort4(h0, h1, h2, h3);
            *(ushort4*)&Al[base] = make_ushort4(bfh(v.x - fb(h0)), bfh(v.y - fb(h1)),
                                                bfh(v.z - fb(h2)), bfh(v.w - fb(h3)));
        }
    }
    __syncthreads();

    int w = t >> 6, lane = t & 63;
    int wr = w >> 2, wc = w & 3;   // wave tile: rows wr*32..+31, cols wc*64..+63 (head wc)
    f32x4 acc[2][4];
#pragma unroll
    for (int mi = 0; mi < 2; ++mi)
#pragma unroll
        for (int nf = 0; nf < 4; ++nf) acc[mi][nf] = f32x4{0.f, 0.f, 0.f, 0.f};

#pragma unroll
    for (int kstep = 0; kstep < 4; ++kstep) {
        bf16x8 a_h[2], a_l[2];
#pragma unroll
        for (int mi = 0; mi < 2; ++mi) {
            int slot = (((wr * 2 + mi) * 4 + kstep) * 64 + lane) * 8;
            a_h[mi] = *(const bf16x8*)&Ah[slot];
            a_l[mi] = *(const bf16x8*)&Al[slot];
        }
#pragma unroll
        for (int nf = 0; nf < 4; ++nf) {
            int slot = (((wc * 4 + nf) * 4 + kstep) * 64 + lane) * 8;
            bf16x8 b_h = *(const bf16x8*)&W1fh[slot];
            bf16x8 b_l = *(const bf16x8*)&W1fl[slot];
#pragma unroll
            for (int mi = 0; mi < 2; ++mi) {
                acc[mi][nf] = __builtin_amdgcn_mfma_f32_16x16x32_bf16(a_h[mi], b_h, acc[mi][nf], 0, 0, 0);
                acc[mi][nf] = __builtin_amdgcn_mfma_f32_16x16x32_bf16(a_h[mi], b_l, acc[mi][nf], 0, 0, 0);
                acc[mi][nf] = __builtin_amdgcn_mfma_f32_16x16x32_bf16(a_l[mi], b_h, acc[mi][nf], 0, 0, 0);
            }
        }
    }

    int fq = lane >> 4, fr = lane & 15;
#pragma unroll
    for (int mi = 0; mi < 2; ++mi) {
#pragma unroll
        for (int j = 0; j < 4; ++j) {
            int r = m0 + wr * 32 + mi * 16 + fq * 4 + j;
            if (r >= N_NODES) continue;
#pragma unroll
            for (int nf = 0; nf < 4; ++nf) {
                int c = wc * 64 + nf * 16 + fr;
                feat1b[(size_t)r * L1_OUT + c] = bfh(acc[mi][nf][j]);
            }
        }
    }

    float al_v[4], ar_v[4];
#pragma unroll
    for (int nf = 0; nf < 4; ++nf) {
        al_v[nf] = al1[wc * 64 + nf * 16 + fr];
        ar_v[nf] = ar1[wc * 64 + nf * 16 + fr];
    }
#pragma unroll
    for (int mi = 0; mi < 2; ++mi) {
#pragma unroll
        for (int j = 0; j < 4; ++j) {
            float l = 0.f, r = 0.f;
#pragma unroll
            for (int nf = 0; nf < 4; ++nf) {
                l += acc[mi][nf][j] * al_v[nf];
                r += acc[mi][nf][j] * ar_v[nf];
            }
#pragma unroll
            for (int off = 1; off < 16; off <<= 1) {
                l += __shfl_xor(l, off, 64);
                r += __shfl_xor(r, off, 64);
            }
            int rr = m0 + wr * 32 + mi * 16 + fq * 4 + j;
            if (fr == 0 && rr < N_NODES) {
                el1[rr * HEADS + wc] = l;
                er1[rr * HEADS + wc] = r;
            }
        }
    }
}

// ---------------- layer2 fused: gather1 (into LDS A-frags, hi-only) + gemm2 MFMA + el2/er2 ----------------
// Block = 512 threads = 8 waves, 32 dsts. Phase 0 hoists ALL 4 dsts' score chains (small
// L2-resident loads, independent -> overlapped issue); phase 1 aggregates feature rows
// strictly one dst at a time (keeps the single-gather-stream L2 behavior of round 7).
__global__ __launch_bounds__(512, 8) void layer2_kernel(const int* __restrict__ row,
                                                        const int* __restrict__ perm_src,
                                                        const float* __restrict__ el1,
                                                        const float* __restrict__ er1,
                                                        const unsigned short* __restrict__ feat1b,
                                                        const float* __restrict__ b1,
                                                        const unsigned short* __restrict__ W2fh,
                                                        const unsigned short* __restrict__ W2fl,
                                                        const float* __restrict__ al2,
                                                        const float* __restrict__ ar2,
                                                        unsigned short* __restrict__ feat2b,
                                                        float* __restrict__ el2,
                                                        float* __restrict__ er2) {
    __shared__ unsigned short Ah[2 * 8 * 64 * 8];   // 16 KB (swizzled slots), hi-only A
    __shared__ float pl[2][4][16], pr[2][4][16];    // [mi][ntile][row]
    int t = threadIdx.x;
    int w = t >> 6, lane = t & 63;
    int n0 = blockIdx.x * 32;
    int h = lane >> 4, jj = lane & 15;

    float4 b1v = *(const float4*)&b1[lane * 4];   // channels lane*4..+3
    const ushort4* f4 = (const ushort4*)feat1b;

    // ---- phase 0: score chains for all 4 dsts (independent, small loads) ----
    int sreg[4];
    float alf[4];
    int basev[4];
    int degv[4];
#pragma unroll
    for (int it = 0; it < 4; ++it) {
        int d = n0 + it * 8 + w;
        bool valid = d < N_NODES;
        int b0 = valid ? row[d] : 0;
        int b1x = valid ? row[d + 1] : 0;
        int deg = valid ? (b1x - b0) : 0;
        basev[it] = b0;
        degv[it] = deg;
        bool fast = deg > 0 && deg <= 16;
        int sr = (fast && jj < deg) ? perm_src[b0 + jj] : 0;
        float er_d = fast ? er1[d * HEADS + h] : 0.f;
        float sc = (fast && jj < deg) ? leaky(el1[sr * HEADS + h] + er_d) : -1e30f;
        sreg[it] = sr;
        alf[it] = fast ? alpha16(sc, deg, jj) : 0.f;
    }

    // ---- phase 1: aggregate feature rows, one dst at a time; write LDS A-frags ----
#pragma unroll
    for (int it = 0; it < 4; ++it) {
        int d = n0 + it * 8 + w;
        int deg = degv[it];
        float4 acc = {0.f, 0.f, 0.f, 0.f};
        if (deg > 0 && deg <= 16) {
            acc = aggregate_fast(deg, sreg[it], alf[it], f4, lane);
        } else if (deg > 16) {
            acc = aggregate_slow(d, basev[it], deg, perm_src, el1, er1, f4, lane);
        }
        if (d < N_NODES) {
            acc.x += b1v.x; acc.y += b1v.y; acc.z += b1v.z; acc.w += b1v.w;
        }
        // write row m = it*8+w, channels lane*4..+3 into swizzled A-frag layout (hi only)
        int m = it * 8 + w;
        int mfrag = m >> 4, mrow = m & 15;
        int c = lane * 4;
        int kstep = c >> 5;
        int g = (c & 31) >> 3;
        int u = (mfrag * 8 + kstep) * 64 + mrow + 16 * g;
        int basei = swzA(u) * 8 + (c & 7);
        *(ushort4*)&Ah[basei] = make_ushort4(bfh(acc.x), bfh(acc.y), bfh(acc.z), bfh(acc.w));
    }
    __syncthreads();

    // ---- phase 2: gemm2 MFMA; wave = (mi, ntile), 16x16 output each ----
    int mi = w & 1, ntile = w >> 1;
    f32x4 acc2 = f32x4{0.f, 0.f, 0.f, 0.f};

#pragma unroll
    for (int ks = 0; ks < 8; ++ks) {
        int aslot = swzA((mi * 8 + ks) * 64 + lane) * 8;
        bf16x8 a_h = *(const bf16x8*)&Ah[aslot];
        int slot = ((ntile * 8 + ks) * 64 + lane) * 8;
        bf16x8 b_h = *(const bf16x8*)&W2fh[slot];
        bf16x8 b_l = *(const bf16x8*)&W2fl[slot];
        acc2 = __builtin_amdgcn_mfma_f32_16x16x32_bf16(a_h, b_h, acc2, 0, 0, 0);
        acc2 = __builtin_amdgcn_mfma_f32_16x16x32_bf16(a_h, b_l, acc2, 0, 0, 0);
    }

    int fq = lane >> 4, fr = lane & 15;
#pragma unroll
    for (int j = 0; j < 4; ++j) {
        int r = n0 + mi * 16 + fq * 4 + j;
        if (r < N_NODES) {
            int c = ntile * 16 + fr;
            feat2b[(size_t)r * OUT_DIM + c] = bfh(acc2[j]);
        }
    }

    // fused el2/er2: per-wave partial over 16 cols, combine 4 ntiles in LDS
    float al_v = al2[ntile * 16 + fr];
    float ar_v = ar2[ntile * 16 + fr];
#pragma unroll
    for (int j = 0; j < 4; ++j) {
        float l = acc2[j] * al_v;
        float r = acc2[j] * ar_v;
#pragma unroll
        for (int off = 1; off < 16; off <<= 1) {
            l += __shfl_xor(l, off, 64);
            r += __shfl_xor(r, off, 64);
        }
        if (fr == 0) {
            pl[mi][ntile][fq * 4 + j] = l;
            pr[mi][ntile][fq * 4 + j] = r;
        }
    }
    __syncthreads();
    if (t < 32) {
        int n = n0 + t;
        if (n < N_NODES) {
            int mi2 = t >> 4, rr = t & 15;
            el2[n] = pl[mi2][0][rr] + pl[mi2][1][rr] + pl[mi2][2][rr] + pl[mi2][3][rr];
            er2[n] = pr[mi2][0][rr] + pr[mi2][1][rr] + pr[mi2][2][rr] + pr[mi2][3][rr];
        }
    }
}

// ---------------- gather2: register softmax + aggregate + bias, 4 dsts/block, no LDS ----------------
__global__ __launch_bounds__(256) void gather2_kernel(const int* __restrict__ row,
                                                      const int* __restrict__ perm_src,
                                                      const float* __restrict__ el2,
                                                      const float* __restrict__ er2,
                                                      const unsigned short* __restrict__ feat2b,
                                                      const float* __restrict__ b2,
                                                      float* __restrict__ out) {
    int tid = threadIdx.x;
    int w = tid >> 6, lane = tid & 63;
    int d = blockIdx.x * 4 + w;
    int base = row[d], deg = row[d + 1] - base;
    float bias = b2[lane];
    if (deg == 0) {
        out[(size_t)d * OUT_DIM + lane] = bias;
        return;
    }
    if (deg <= 64) {
        int s_reg = (lane < deg) ? perm_src[base + lane] : 0;
        float er_d = er2[d];
        float sc = (lane < deg) ? leaky(el2[s_reg] + er_d) : -1e30f;
        float m = sc;
#pragma unroll
        for (int off = 1; off < 64; off <<= 1) m = fmaxf(m, __shfl_xor(m, off, 64));
        float ex = (lane < deg) ? __expf(sc - m) : 0.f;
        float ss = ex;
#pragma unroll
        for (int off = 1; off < 64; off <<= 1) ss += __shfl_xor(ss, off, 64);
        float alpha = ex / ss;
        float a0 = 0.f, a1 = 0.f, a2 = 0.f, a3 = 0.f;
        float a4 = 0.f, a5 = 0.f, a6 = 0.f, a7 = 0.f;
        int j = 0;
        for (; j + 7 < deg; j += 8) {
            int s0 = __shfl(s_reg, j),     s1 = __shfl(s_reg, j + 1);
            int s2 = __shfl(s_reg, j + 2), s3 = __shfl(s_reg, j + 3);
            int s4 = __shfl(s_reg, j + 4), s5 = __shfl(s_reg, j + 5);
            int s6 = __shfl(s_reg, j + 6), s7 = __shfl(s_reg, j + 7);
            float w0 = __shfl(alpha, j),     w1 = __shfl(alpha, j + 1);
            float w2 = __shfl(alpha, j + 2), w3 = __shfl(alpha, j + 3);
            float w4 = __shfl(alpha, j + 4), w5 = __shfl(alpha, j + 5);
            float w6 = __shfl(alpha, j + 6), w7 = __shfl(alpha, j + 7);
            a0 += w0 * fb(feat2b[(size_t)s0 * OUT_DIM + lane]);
            a1 += w1 * fb(feat2b[(size_t)s1 * OUT_DIM + lane]);
            a2 += w2 * fb(feat2b[(size_t)s2 * OUT_DIM + lane]);
            a3 += w3 * fb(feat2b[(size_t)s3 * OUT_DIM + lane]);
            a4 += w4 * fb(feat2b[(size_t)s4 * OUT_DIM + lane]);
            a5 += w5 * fb(feat2b[(size_t)s5 * OUT_DIM + lane]);
            a6 += w6 * fb(feat2b[(size_t)s6 * OUT_DIM + lane]);
            a7 += w7 * fb(feat2b[(size_t)s7 * OUT_DIM + lane]);
        }
        for (; j + 3 < deg; j += 4) {
            int s0 = __shfl(s_reg, j),     s1 = __shfl(s_reg, j + 1);
            int s2 = __shfl(s_reg, j + 2), s3 = __shfl(s_reg, j + 3);
            float w0 = __shfl(alpha, j),     w1 = __shfl(alpha, j + 1);
            float w2 = __shfl(alpha, j + 2), w3 = __shfl(alpha, j + 3);
            a0 += w0 * fb(feat2b[(size_t)s0 * OUT_DIM + lane]);
            a1 += w1 * fb(feat2b[(size_t)s1 * OUT_DIM + lane]);
            a2 += w2 * fb(feat2b[(size_t)s2 * OUT_DIM + lane]);
            a3 += w3 * fb(feat2b[(size_t)s3 * OUT_DIM + lane]);
        }
        for (; j < deg; ++j) {
            int s0 = __shfl(s_reg, j);
            float w0 = __shfl(alpha, j);
            a0 += w0 * fb(feat2b[(size_t)s0 * OUT_DIM + lane]);
        }
        out[(size_t)d * OUT_DIM + lane] = a0 + a1 + a2 + a3 + a4 + a5 + a6 + a7 + bias;
    } else {
        // rare fallback deg > 64: recompute path
        float er_d = er2[d];
        float m = -1e30f;
        for (int j = lane; j < deg; j += 64)
            m = fmaxf(m, leaky(el2[perm_src[base + j]] + er_d));
#pragma unroll
        for (int off = 1; off < 64; off <<= 1) m = fmaxf(m, __shfl_xor(m, off, 64));
        float ss = 0.f;
        for (int j = lane; j < deg; j += 64)
            ss += __expf(leaky(el2[perm_src[base + j]] + er_d) - m);
#pragma unroll
        for (int off = 1; off < 64; off <<= 1) ss += __shfl_xor(ss, off, 64);
        float inv = 1.f / ss;
        float a0 = 0.f;
        for (int j = 0; j < deg; ++j) {
            int s = perm_src[base + j];
            float a = __expf(leaky(el2[s] + er_d) - m) * inv;
            a0 += a * fb(feat2b[(size_t)s * OUT_DIM + lane]);
        }
        out[(size_t)d * OUT_DIM + lane] = a0 + bias;
    }
}

extern "C" void kernel_launch(void* const* d_in, const int* in_sizes, int n_in,
                              void* d_out, int out_size, void* d_ws, size_t ws_size,
                              hipStream_t stream) {
    const float* features = (const float*)d_in[0];
    const int* src = (const int*)d_in[1];
    const int* dst = (const int*)d_in[2];
    const float* W1 = (const float*)d_in[3];
    const float* al1 = (const float*)d_in[4];
    const float* ar1 = (const float*)d_in[5];
    const float* b1 = (const float*)d_in[6];
    const float* W2 = (const float*)d_in[7];
    const float* al2 = (const float*)d_in[8];
    const float* ar2 = (const float*)d_in[9];
    const float* b2 = (const float*)d_in[10];
    float* out = (float*)d_out;

    // workspace layout
    float* ws = (float*)d_ws;
    float* el1 = ws;                                           // N*4
    float* er1 = el1 + N_NODES * HEADS;                        // N*4
    float* el2 = er1 + N_NODES * HEADS;                        // N
    float* er2 = el2 + N_NODES;                                // N
    unsigned short* feat1b = (unsigned short*)(er2 + N_NODES); // N*256 bf16
    unsigned short* feat2b = feat1b + (size_t)N_NODES * L1_OUT;// N*64 bf16
    unsigned short* W1fh = feat2b + (size_t)N_NODES * OUT_DIM; // 32768
    unsigned short* W1fl = W1fh + 32768;                       // 32768
    unsigned short* W2fh = W1fl + 32768;                       // 16384
    unsigned short* W2fl = W2fh + 16384;                       // 16384
    int* cnt = (int*)(W2fl + 16384);                           // N
    int* fc = cnt + N_NODES;                                   // N
    int* texcl = fc + N_NODES;                                 // N
    int* bsum = texcl + N_NODES;                               // 256
    int* bexcl = bsum + 256;                                   // 256
    int* row = bexcl + 256;                                    // N+1
    int* perm_src = row + N_NODES + 1;                         // E

    const int nscan = (N_NODES + SCAN_B - 1) / SCAN_B;   // 196

    hipMemsetAsync(cnt, 0, (size_t)2 * N_NODES * sizeof(int), stream);  // cnt + fc

    // CSR build + weight prep
    hist_wprep_kernel<<<HIST_B + 24, 256, 0, stream>>>(dst, cnt, W1, W2, W1fh, W1fl, W2fh, W2fl);
    scanA_kernel<<<nscan, SCAN_B, 0, stream>>>(cnt, texcl, bsum);
    scanB_kernel<<<1, SCAN_B, 0, stream>>>(bsum, bexcl, nscan);
    scanC_kernel<<<(N_NODES + 255) / 256, 256, 0, stream>>>(texcl, bexcl, row);
    fill_kernel<<<(N_EDGES + 255) / 256, 256, 0, stream>>>(src, dst, row, fc, perm_src);

    // layer 1 GEMM (+el1/er1)
    gemm1_kernel<<<(N_NODES + 63) / 64, 512, 0, stream>>>(features, W1fh, W1fl, al1, ar1,
                                                          feat1b, el1, er1);
    // layer 1 gather fused with layer 2 GEMM (+el2/er2)
    layer2_kernel<<<(N_NODES + 31) / 32, 512, 0, stream>>>(row, perm_src, el1, er1, feat1b,
                                                           b1, W2fh, W2fl, al2, ar2,
                                                           feat2b, el2, er2);
    // layer 2 gather (+bias)
    gather2_kernel<<<N_NODES / 4, 256, 0, stream>>>(row, perm_src, el2, er2, feat2b, b2, out);
}

// Round 11
// 164.546 us; speedup vs baseline: 1.0257x; 1.0257x over previous
//
#include <hip/hip_runtime.h>
#include <hip/hip_bf16.h>

#define N_NODES 50000
#define N_EDGES 400000
#define IN_DIM 128
#define HID 64
#define HEADS 4
#define L1_OUT (HEADS * HID)   // 256
#define OUT_DIM 64
#define NEG_SLOPE 0.2f
#define SCAN_B 256
#define HIST_B 1563            // ceil(400000/256)

typedef short bf16x8 __attribute__((ext_vector_type(8)));
typedef float f32x4 __attribute__((ext_vector_type(4)));

__device__ __forceinline__ float leaky(float x) { return x > 0.f ? x : NEG_SLOPE * x; }

// RNE float->bf16 bits, bf16 bits->float
__device__ __forceinline__ unsigned short bfh(float x) {
    unsigned u = __float_as_uint(x);
    return (unsigned short)((u + 0x7fffu + ((u >> 16) & 1u)) >> 16);
}
__device__ __forceinline__ float fb(unsigned short h) {
    return __uint_as_float(((unsigned)h) << 16);
}

// LDS A-frag slot swizzle (16B-slot index u): spreads kstep/g into the bank bits.
__device__ __forceinline__ int swzA(int u) {
    return u ^ (((u >> 6) & 7) ^ (((u >> 4) & 3) << 1));
}

#define FMA4(A, wv, g) { A.x += wv * fb(g.x); A.y += wv * fb(g.y); A.z += wv * fb(g.z); A.w += wv * fb(g.w); }

// ---------------- CSR hist + W fragment prep (merged) ----------------
__global__ void hist_wprep_kernel(const int* __restrict__ dst, int* __restrict__ cnt,
                                  const float* __restrict__ W1, const float* __restrict__ W2,
                                  unsigned short* __restrict__ W1fh, unsigned short* __restrict__ W1fl,
                                  unsigned short* __restrict__ W2fh, unsigned short* __restrict__ W2fl) {
    int bid = blockIdx.x;
    if (bid < HIST_B) {
        int e = bid * 256 + threadIdx.x;
        if (e < N_EDGES) atomicAdd(&cnt[dst[e]], 1);
        return;
    }
    int s = (bid - HIST_B) * 256 + threadIdx.x;
    if (s < 4096) {
        int lane = s & 63, ks = (s >> 6) & 3, ntile = s >> 8;
        int n = ntile * 16 + (lane & 15);
        int kb = ks * 32 + (lane >> 4) * 8;
#pragma unroll
        for (int j = 0; j < 8; ++j) {
            float w = W1[(kb + j) * L1_OUT + n];
            unsigned short h = bfh(w);
            W1fh[s * 8 + j] = h;
            W1fl[s * 8 + j] = bfh(w - fb(h));
        }
    } else if (s < 6144) {
        int s2 = s - 4096;
        int lane = s2 & 63, ks = (s2 >> 6) & 7, ntile = s2 >> 9;
        int n = ntile * 16 + (lane & 15);
        int kb = ks * 32 + (lane >> 4) * 8;
#pragma unroll
        for (int j = 0; j < 8; ++j) {
            float w = W2[(kb + j) * OUT_DIM + n];
            unsigned short h = bfh(w);
            W2fh[s2 * 8 + j] = h;
            W2fl[s2 * 8 + j] = bfh(w - fb(h));
        }
    }
}

__global__ void scanA_kernel(const int* __restrict__ cnt, int* __restrict__ texcl,
                             int* __restrict__ bsum) {
    __shared__ int sh[SCAN_B];
    int tid = threadIdx.x;
    int i = blockIdx.x * SCAN_B + tid;
    int v = (i < N_NODES) ? cnt[i] : 0;
    sh[tid] = v;
    __syncthreads();
    for (int off = 1; off < SCAN_B; off <<= 1) {
        int t = (tid >= off) ? sh[tid - off] : 0;
        __syncthreads();
        sh[tid] += t;
        __syncthreads();
    }
    if (i < N_NODES) texcl[i] = sh[tid] - v;
    if (tid == SCAN_B - 1) bsum[blockIdx.x] = sh[tid];
}

// merged scanB+scanC: block b reduces its own prefix of bsum, then writes row
__global__ void scanC_kernel(const int* __restrict__ texcl, const int* __restrict__ bsum,
                             int* __restrict__ row, int nb) {
    __shared__ int sh[SCAN_B];
    int b = blockIdx.x;
    int tid = threadIdx.x;
    sh[tid] = (tid < b && tid < nb) ? bsum[tid] : 0;
    __syncthreads();
#pragma unroll
    for (int off = 128; off > 0; off >>= 1) {
        if (tid < off) sh[tid] += sh[tid + off];
        __syncthreads();
    }
    int prefix = sh[0];
    int i = b * SCAN_B + tid;
    if (i < N_NODES) row[i] = texcl[i] + prefix;
    if (b == 0 && tid == 0) row[N_NODES] = N_EDGES;
}

__global__ void fill_kernel(const int* __restrict__ src, const int* __restrict__ dst,
                            const int* __restrict__ row, int* __restrict__ fc,
                            int* __restrict__ perm_src) {
    int e = blockIdx.x * blockDim.x + threadIdx.x;
    if (e >= N_EDGES) return;
    int d = dst[e];
    int p = row[d] + atomicAdd(&fc[d], 1);
    perm_src[p] = src[e];
}

// ---------------- gemm1 (MFMA): feat1b = bf16(X @ W1) + fused el1/er1 ----------------
// A-side hi-only: X bf16-rounding error (~2^-9 rel) is sub-dominant to feat1b bf16 storage.
__global__ __launch_bounds__(512) void gemm1_kernel(const float* __restrict__ X,
                                                    const unsigned short* __restrict__ W1fh,
                                                    const unsigned short* __restrict__ W1fl,
                                                    const float* __restrict__ al1,
                                                    const float* __restrict__ ar1,
                                                    unsigned short* __restrict__ feat1b,
                                                    float* __restrict__ el1,
                                                    float* __restrict__ er1) {
    __shared__ unsigned short Ah[4 * 4 * 64 * 8];   // [mfrag][kstep][lane][j] 16 KB
    int t = threadIdx.x;
    int m0 = blockIdx.x * 64;

    {
        int m = t >> 3;
        int k0 = (t & 7) * 16;
        int mfrag = m >> 4, mrow = m & 15;
        bool valid = (m0 + m) < N_NODES;
        const float4* xr = (const float4*)&X[(size_t)(m0 + m) * IN_DIM];
#pragma unroll
        for (int g = 0; g < 4; ++g) {
            int k = k0 + g * 4;
            float4 v = valid ? xr[k >> 2] : float4{0.f, 0.f, 0.f, 0.f};
            int kstep = k >> 5, kk = k & 31;
            int lane = mrow + 16 * (kk >> 3);
            int j0 = kk & 7;
            int base = ((mfrag * 4 + kstep) * 64 + lane) * 8 + j0;
            *(ushort4*)&Ah[base] = make_ushort4(bfh(v.x), bfh(v.y), bfh(v.z), bfh(v.w));
        }
    }
    __syncthreads();

    int w = t >> 6, lane = t & 63;
    int wr = w >> 2, wc = w & 3;   // wave tile: rows wr*32..+31, cols wc*64..+63 (head wc)
    f32x4 acc[2][4];
#pragma unroll
    for (int mi = 0; mi < 2; ++mi)
#pragma unroll
        for (int nf = 0; nf < 4; ++nf) acc[mi][nf] = f32x4{0.f, 0.f, 0.f, 0.f};

#pragma unroll
    for (int kstep = 0; kstep < 4; ++kstep) {
        bf16x8 a_h[2];
#pragma unroll
        for (int mi = 0; mi < 2; ++mi) {
            int slot = (((wr * 2 + mi) * 4 + kstep) * 64 + lane) * 8;
            a_h[mi] = *(const bf16x8*)&Ah[slot];
        }
#pragma unroll
        for (int nf = 0; nf < 4; ++nf) {
            int slot = (((wc * 4 + nf) * 4 + kstep) * 64 + lane) * 8;
            bf16x8 b_h = *(const bf16x8*)&W1fh[slot];
            bf16x8 b_l = *(const bf16x8*)&W1fl[slot];
#pragma unroll
            for (int mi = 0; mi < 2; ++mi) {
                acc[mi][nf] = __builtin_amdgcn_mfma_f32_16x16x32_bf16(a_h[mi], b_h, acc[mi][nf], 0, 0, 0);
                acc[mi][nf] = __builtin_amdgcn_mfma_f32_16x16x32_bf16(a_h[mi], b_l, acc[mi][nf], 0, 0, 0);
            }
        }
    }

    int fq = lane >> 4, fr = lane & 15;
#pragma unroll
    for (int mi = 0; mi < 2; ++mi) {
#pragma unroll
        for (int j = 0; j < 4; ++j) {
            int r = m0 + wr * 32 + mi * 16 + fq * 4 + j;
            if (r >= N_NODES) continue;
#pragma unroll
            for (int nf = 0; nf < 4; ++nf) {
                int c = wc * 64 + nf * 16 + fr;
                feat1b[(size_t)r * L1_OUT + c] = bfh(acc[mi][nf][j]);
            }
        }
    }

    float al_v[4], ar_v[4];
#pragma unroll
    for (int nf = 0; nf < 4; ++nf) {
        al_v[nf] = al1[wc * 64 + nf * 16 + fr];
        ar_v[nf] = ar1[wc * 64 + nf * 16 + fr];
    }
#pragma unroll
    for (int mi = 0; mi < 2; ++mi) {
#pragma unroll
        for (int j = 0; j < 4; ++j) {
            float l = 0.f, r = 0.f;
#pragma unroll
            for (int nf = 0; nf < 4; ++nf) {
                l += acc[mi][nf][j] * al_v[nf];
                r += acc[mi][nf][j] * ar_v[nf];
            }
#pragma unroll
            for (int off = 1; off < 16; off <<= 1) {
                l += __shfl_xor(l, off, 64);
                r += __shfl_xor(r, off, 64);
            }
            int rr = m0 + wr * 32 + mi * 16 + fq * 4 + j;
            if (fr == 0 && rr < N_NODES) {
                el1[rr * HEADS + wc] = l;
                er1[rr * HEADS + wc] = r;
            }
        }
    }
}

// ---------------- layer2 fused: gather1 (into LDS A-frags, hi-only) + gemm2 MFMA + el2/er2 ----------------
// Block = 512 threads = 8 waves, owns 32 consecutive dsts (4 iterations x 8 waves, sequential).
__global__ __launch_bounds__(512, 8) void layer2_kernel(const int* __restrict__ row,
                                                        const int* __restrict__ perm_src,
                                                        const float* __restrict__ el1,
                                                        const float* __restrict__ er1,
                                                        const unsigned short* __restrict__ feat1b,
                                                        const float* __restrict__ b1,
                                                        const unsigned short* __restrict__ W2fh,
                                                        const unsigned short* __restrict__ W2fl,
                                                        const float* __restrict__ al2,
                                                        const float* __restrict__ ar2,
                                                        unsigned short* __restrict__ feat2b,
                                                        float* __restrict__ el2,
                                                        float* __restrict__ er2) {
    __shared__ unsigned short Ah[2 * 8 * 64 * 8];   // 16 KB (swizzled slots), hi-only A
    __shared__ float pl[2][4][16], pr[2][4][16];    // [mi][ntile][row]
    int t = threadIdx.x;
    int w = t >> 6, lane = t & 63;
    int n0 = blockIdx.x * 32;

    float4 b1v = *(const float4*)&b1[lane * 4];   // channels lane*4..+3
    const ushort4* f4 = (const ushort4*)feat1b;

    // ---- phase 1: aggregate 32 dst rows into LDS A-fragments (sequential) ----
#pragma unroll 1
    for (int it = 0; it < 4; ++it) {
        int d = n0 + it * 8 + w;
        float4 acc = {0.f, 0.f, 0.f, 0.f};
        bool valid = d < N_NODES;
        if (valid) {
            int base = row[d], deg = row[d + 1] - base;
            if (deg > 0 && deg <= 16) {
                // register softmax: 16-lane group per head, lane jj = edge jj
                int h = lane >> 4, jj = lane & 15;
                int s_reg = (jj < deg) ? perm_src[base + jj] : 0;
                float er_d = er1[d * HEADS + h];
                float sc = (jj < deg) ? leaky(el1[s_reg * HEADS + h] + er_d) : -1e30f;
                float m = sc;
                m = fmaxf(m, __shfl_xor(m, 1, 64));
                m = fmaxf(m, __shfl_xor(m, 2, 64));
                m = fmaxf(m, __shfl_xor(m, 4, 64));
                m = fmaxf(m, __shfl_xor(m, 8, 64));
                float ex = (jj < deg) ? __expf(sc - m) : 0.f;
                float ss = ex;
                ss += __shfl_xor(ss, 1, 64);
                ss += __shfl_xor(ss, 2, 64);
                ss += __shfl_xor(ss, 4, 64);
                ss += __shfl_xor(ss, 8, 64);
                float alpha = ex / ss;
                int hb = lane & 48;
                float4 A0 = {0.f,0.f,0.f,0.f}, A1 = {0.f,0.f,0.f,0.f};
                float4 A2 = {0.f,0.f,0.f,0.f}, A3 = {0.f,0.f,0.f,0.f};
                int j = 0;
                for (; j + 3 < deg; j += 4) {
                    int s0 = __shfl(s_reg, j), s1 = __shfl(s_reg, j + 1);
                    int s2 = __shfl(s_reg, j + 2), s3 = __shfl(s_reg, j + 3);
                    float a0 = __shfl(alpha, hb + j), a1 = __shfl(alpha, hb + j + 1);
                    float a2 = __shfl(alpha, hb + j + 2), a3 = __shfl(alpha, hb + j + 3);
                    ushort4 f0 = f4[(size_t)s0 * 64 + lane];
                    ushort4 f1 = f4[(size_t)s1 * 64 + lane];
                    ushort4 f2 = f4[(size_t)s2 * 64 + lane];
                    ushort4 f3 = f4[(size_t)s3 * 64 + lane];
                    FMA4(A0, a0, f0); FMA4(A1, a1, f1); FMA4(A2, a2, f2); FMA4(A3, a3, f3);
                }
                for (; j < deg; ++j) {
                    int s0 = __shfl(s_reg, j);
                    float a0 = __shfl(alpha, hb + j);
                    ushort4 f0 = f4[(size_t)s0 * 64 + lane];
                    FMA4(A0, a0, f0);
                }
                acc.x = A0.x + A1.x + A2.x + A3.x;
                acc.y = A0.y + A1.y + A2.y + A3.y;
                acc.z = A0.z + A1.z + A2.z + A3.z;
                acc.w = A0.w + A1.w + A2.w + A3.w;
            } else if (deg > 16) {
                // rare fallback: strided per-head stats, serial recompute aggregation
                float mh0, mh1, mh2, mh3, iv0, iv1, iv2, iv3;
#pragma unroll
                for (int h = 0; h < 4; ++h) {
                    float er_dh = er1[d * HEADS + h];
                    float m = -1e30f;
                    for (int j = lane; j < deg; j += 64)
                        m = fmaxf(m, leaky(el1[perm_src[base + j] * HEADS + h] + er_dh));
#pragma unroll
                    for (int off = 1; off < 64; off <<= 1) m = fmaxf(m, __shfl_xor(m, off, 64));
                    float ss = 0.f;
                    for (int j = lane; j < deg; j += 64)
                        ss += __expf(leaky(el1[perm_src[base + j] * HEADS + h] + er_dh) - m);
#pragma unroll
                    for (int off = 1; off < 64; off <<= 1) ss += __shfl_xor(ss, off, 64);
                    float iv = 1.f / ss;
                    if (h == 0) { mh0 = m; iv0 = iv; }
                    else if (h == 1) { mh1 = m; iv1 = iv; }
                    else if (h == 2) { mh2 = m; iv2 = iv; }
                    else { mh3 = m; iv3 = iv; }
                }
                int hh = lane >> 4;
                float m_s = hh == 0 ? mh0 : hh == 1 ? mh1 : hh == 2 ? mh2 : mh3;
                float iv_s = hh == 0 ? iv0 : hh == 1 ? iv1 : hh == 2 ? iv2 : iv3;
                float er_s = er1[d * HEADS + hh];
                for (int j = 0; j < deg; ++j) {
                    int s = perm_src[base + j];
                    float a = __expf(leaky(el1[s * HEADS + hh] + er_s) - m_s) * iv_s;
                    ushort4 f0 = f4[(size_t)s * 64 + lane];
                    FMA4(acc, a, f0);
                }
            }
            // deg==0: acc stays 0
            acc.x += b1v.x; acc.y += b1v.y; acc.z += b1v.z; acc.w += b1v.w;
        }
        // write row m = it*8+w, channels lane*4..+3 into swizzled A-frag layout (hi only)
        int m = it * 8 + w;
        int mfrag = m >> 4, mrow = m & 15;
        int c = lane * 4;
        int kstep = c >> 5;
        int g = (c & 31) >> 3;
        int u = (mfrag * 8 + kstep) * 64 + mrow + 16 * g;
        int basei = swzA(u) * 8 + (c & 7);
        *(ushort4*)&Ah[basei] = make_ushort4(bfh(acc.x), bfh(acc.y), bfh(acc.z), bfh(acc.w));
    }
    __syncthreads();

    // ---- phase 2: gemm2 MFMA; wave = (mi, ntile), 16x16 output each ----
    int mi = w & 1, ntile = w >> 1;
    f32x4 acc2 = f32x4{0.f, 0.f, 0.f, 0.f};

#pragma unroll
    for (int ks = 0; ks < 8; ++ks) {
        int aslot = swzA((mi * 8 + ks) * 64 + lane) * 8;
        bf16x8 a_h = *(const bf16x8*)&Ah[aslot];
        int slot = ((ntile * 8 + ks) * 64 + lane) * 8;
        bf16x8 b_h = *(const bf16x8*)&W2fh[slot];
        bf16x8 b_l = *(const bf16x8*)&W2fl[slot];
        acc2 = __builtin_amdgcn_mfma_f32_16x16x32_bf16(a_h, b_h, acc2, 0, 0, 0);
        acc2 = __builtin_amdgcn_mfma_f32_16x16x32_bf16(a_h, b_l, acc2, 0, 0, 0);
    }

    int fq = lane >> 4, fr = lane & 15;
#pragma unroll
    for (int j = 0; j < 4; ++j) {
        int r = n0 + mi * 16 + fq * 4 + j;
        if (r < N_NODES) {
            int c = ntile * 16 + fr;
            feat2b[(size_t)r * OUT_DIM + c] = bfh(acc2[j]);
        }
    }

    // fused el2/er2: per-wave partial over 16 cols, combine 4 ntiles in LDS
    float al_v = al2[ntile * 16 + fr];
    float ar_v = ar2[ntile * 16 + fr];
#pragma unroll
    for (int j = 0; j < 4; ++j) {
        float l = acc2[j] * al_v;
        float r = acc2[j] * ar_v;
#pragma unroll
        for (int off = 1; off < 16; off <<= 1) {
            l += __shfl_xor(l, off, 64);
            r += __shfl_xor(r, off, 64);
        }
        if (fr == 0) {
            pl[mi][ntile][fq * 4 + j] = l;
            pr[mi][ntile][fq * 4 + j] = r;
        }
    }
    __syncthreads();
    if (t < 32) {
        int n = n0 + t;
        if (n < N_NODES) {
            int mi2 = t >> 4, rr = t & 15;
            el2[n] = pl[mi2][0][rr] + pl[mi2][1][rr] + pl[mi2][2][rr] + pl[mi2][3][rr];
            er2[n] = pr[mi2][0][rr] + pr[mi2][1][rr] + pr[mi2][2][rr] + pr[mi2][3][rr];
        }
    }
}

// ---------------- gather2: register softmax + aggregate + bias, 4 dsts/block, no LDS ----------------
__global__ __launch_bounds__(256) void gather2_kernel(const int* __restrict__ row,
                                                      const int* __restrict__ perm_src,
                                                      const float* __restrict__ el2,
                                                      const float* __restrict__ er2,
                                                      const unsigned short* __restrict__ feat2b,
                                                      const float* __restrict__ b2,
                                                      float* __restrict__ out) {
    int tid = threadIdx.x;
    int w = tid >> 6, lane = tid & 63;
    int d = blockIdx.x * 4 + w;
    int base = row[d], deg = row[d + 1] - base;
    float bias = b2[lane];
    if (deg == 0) {
        out[(size_t)d * OUT_DIM + lane] = bias;
        return;
    }
    if (deg <= 64) {
        int s_reg = (lane < deg) ? perm_src[base + lane] : 0;
        float er_d = er2[d];
        float sc = (lane < deg) ? leaky(el2[s_reg] + er_d) : -1e30f;
        float m = sc;
#pragma unroll
        for (int off = 1; off < 64; off <<= 1) m = fmaxf(m, __shfl_xor(m, off, 64));
        float ex = (lane < deg) ? __expf(sc - m) : 0.f;
        float ss = ex;
#pragma unroll
        for (int off = 1; off < 64; off <<= 1) ss += __shfl_xor(ss, off, 64);
        float alpha = ex / ss;
        float a0 = 0.f, a1 = 0.f, a2 = 0.f, a3 = 0.f;
        float a4 = 0.f, a5 = 0.f, a6 = 0.f, a7 = 0.f;
        int j = 0;
        for (; j + 7 < deg; j += 8) {
            int s0 = __shfl(s_reg, j),     s1 = __shfl(s_reg, j + 1);
            int s2 = __shfl(s_reg, j + 2), s3 = __shfl(s_reg, j + 3);
            int s4 = __shfl(s_reg, j + 4), s5 = __shfl(s_reg, j + 5);
            int s6 = __shfl(s_reg, j + 6), s7 = __shfl(s_reg, j + 7);
            float w0 = __shfl(alpha, j),     w1 = __shfl(alpha, j + 1);
            float w2 = __shfl(alpha, j + 2), w3 = __shfl(alpha, j + 3);
            float w4 = __shfl(alpha, j + 4), w5 = __shfl(alpha, j + 5);
            float w6 = __shfl(alpha, j + 6), w7 = __shfl(alpha, j + 7);
            a0 += w0 * fb(feat2b[(size_t)s0 * OUT_DIM + lane]);
            a1 += w1 * fb(feat2b[(size_t)s1 * OUT_DIM + lane]);
            a2 += w2 * fb(feat2b[(size_t)s2 * OUT_DIM + lane]);
            a3 += w3 * fb(feat2b[(size_t)s3 * OUT_DIM + lane]);
            a4 += w4 * fb(feat2b[(size_t)s4 * OUT_DIM + lane]);
            a5 += w5 * fb(feat2b[(size_t)s5 * OUT_DIM + lane]);
            a6 += w6 * fb(feat2b[(size_t)s6 * OUT_DIM + lane]);
            a7 += w7 * fb(feat2b[(size_t)s7 * OUT_DIM + lane]);
        }
        for (; j + 3 < deg; j += 4) {
            int s0 = __shfl(s_reg, j),     s1 = __shfl(s_reg, j + 1);
            int s2 = __shfl(s_reg, j + 2), s3 = __shfl(s_reg, j + 3);
            float w0 = __shfl(alpha, j),     w1 = __shfl(alpha, j + 1);
            float w2 = __shfl(alpha, j + 2), w3 = __shfl(alpha, j + 3);
            a0 += w0 * fb(feat2b[(size_t)s0 * OUT_DIM + lane]);
            a1 += w1 * fb(feat2b[(size_t)s1 * OUT_DIM + lane]);
            a2 += w2 * fb(feat2b[(size_t)s2 * OUT_DIM + lane]);
            a3 += w3 * fb(feat2b[(size_t)s3 * OUT_DIM + lane]);
        }
        for (; j < deg; ++j) {
            int s0 = __shfl(s_reg, j);
            float w0 = __shfl(alpha, j);
            a0 += w0 * fb(feat2b[(size_t)s0 * OUT_DIM + lane]);
        }
        out[(size_t)d * OUT_DIM + lane] = a0 + a1 + a2 + a3 + a4 + a5 + a6 + a7 + bias;
    } else {
        // rare fallback deg > 64: recompute path
        float er_d = er2[d];
        float m = -1e30f;
        for (int j = lane; j < deg; j += 64)
            m = fmaxf(m, leaky(el2[perm_src[base + j]] + er_d));
#pragma unroll
        for (int off = 1; off < 64; off <<= 1) m = fmaxf(m, __shfl_xor(m, off, 64));
        float ss = 0.f;
        for (int j = lane; j < deg; j += 64)
            ss += __expf(leaky(el2[perm_src[base + j]] + er_d) - m);
#pragma unroll
        for (int off = 1; off < 64; off <<= 1) ss += __shfl_xor(ss, off, 64);
        float inv = 1.f / ss;
        float a0 = 0.f;
        for (int j = 0; j < deg; ++j) {
            int s = perm_src[base + j];
            float a = __expf(leaky(el2[s] + er_d) - m) * inv;
            a0 += a * fb(feat2b[(size_t)s * OUT_DIM + lane]);
        }
        out[(size_t)d * OUT_DIM + lane] = a0 + bias;
    }
}

extern "C" void kernel_launch(void* const* d_in, const int* in_sizes, int n_in,
                              void* d_out, int out_size, void* d_ws, size_t ws_size,
                              hipStream_t stream) {
    const float* features = (const float*)d_in[0];
    const int* src = (const int*)d_in[1];
    const int* dst = (const int*)d_in[2];
    const float* W1 = (const float*)d_in[3];
    const float* al1 = (const float*)d_in[4];
    const float* ar1 = (const float*)d_in[5];
    const float* b1 = (const float*)d_in[6];
    const float* W2 = (const float*)d_in[7];
    const float* al2 = (const float*)d_in[8];
    const float* ar2 = (const float*)d_in[9];
    const float* b2 = (const float*)d_in[10];
    float* out = (float*)d_out;

    // workspace layout
    float* ws = (float*)d_ws;
    float* el1 = ws;                                           // N*4
    float* er1 = el1 + N_NODES * HEADS;                        // N*4
    float* el2 = er1 + N_NODES * HEADS;                        // N
    float* er2 = el2 + N_NODES;                                // N
    unsigned short* feat1b = (unsigned short*)(er2 + N_NODES); // N*256 bf16
    unsigned short* feat2b = feat1b + (size_t)N_NODES * L1_OUT;// N*64 bf16
    unsigned short* W1fh = feat2b + (size_t)N_NODES * OUT_DIM; // 32768
    unsigned short* W1fl = W1fh + 32768;                       // 32768
    unsigned short* W2fh = W1fl + 32768;                       // 16384
    unsigned short* W2fl = W2fh + 16384;                       // 16384
    int* cnt = (int*)(W2fl + 16384);                           // N
    int* fc = cnt + N_NODES;                                   // N
    int* texcl = fc + N_NODES;                                 // N
    int* bsum = texcl + N_NODES;                               // 256
    int* row = bsum + 256;                                     // N+1
    int* perm_src = row + N_NODES + 1;                         // E

    const int nscan = (N_NODES + SCAN_B - 1) / SCAN_B;   // 196

    hipMemsetAsync(cnt, 0, (size_t)2 * N_NODES * sizeof(int), stream);  // cnt + fc

    // CSR build + weight prep
    hist_wprep_kernel<<<HIST_B + 24, 256, 0, stream>>>(dst, cnt, W1, W2, W1fh, W1fl, W2fh, W2fl);
    scanA_kernel<<<nscan, SCAN_B, 0, stream>>>(cnt, texcl, bsum);
    scanC_kernel<<<nscan, SCAN_B, 0, stream>>>(texcl, bsum, row, nscan);
    fill_kernel<<<(N_EDGES + 255) / 256, 256, 0, stream>>>(src, dst, row, fc, perm_src);

    // layer 1 GEMM (+el1/er1)
    gemm1_kernel<<<(N_NODES + 63) / 64, 512, 0, stream>>>(features, W1fh, W1fl, al1, ar1,
                                                          feat1b, el1, er1);
    // layer 1 gather fused with layer 2 GEMM (+el2/er2)
    layer2_kernel<<<(N_NODES + 31) / 32, 512, 0, stream>>>(row, perm_src, el1, er1, feat1b,
                                                           b1, W2fh, W2fl, al2, ar2,
                                                           feat2b, el2, er2);
    // layer 2 gather (+bias)
    gather2_kernel<<<N_NODES / 4, 256, 0, stream>>>(row, perm_src, el2, er2, feat2b, b2, out);
}

// Round 12
// 163.578 us; speedup vs baseline: 1.0318x; 1.0059x over previous
//
#include <hip/hip_runtime.h>
#include <hip/hip_bf16.h>

#define N_NODES 50000
#define N_EDGES 400000
#define IN_DIM 128
#define HID 64
#define HEADS 4
#define L1_OUT (HEADS * HID)   // 256
#define OUT_DIM 64
#define NEG_SLOPE 0.2f
#define SCAN_B 256
#define HIST_B 1563            // ceil(400000/256)

typedef short bf16x8 __attribute__((ext_vector_type(8)));
typedef float f32x4 __attribute__((ext_vector_type(4)));

__device__ __forceinline__ float leaky(float x) { return x > 0.f ? x : NEG_SLOPE * x; }

// RNE float->bf16 bits, bf16 bits->float
__device__ __forceinline__ unsigned short bfh(float x) {
    unsigned u = __float_as_uint(x);
    return (unsigned short)((u + 0x7fffu + ((u >> 16) & 1u)) >> 16);
}
__device__ __forceinline__ float fb(unsigned short h) {
    return __uint_as_float(((unsigned)h) << 16);
}

// LDS A-frag slot swizzle (16B-slot index u): spreads kstep/g into the bank bits.
__device__ __forceinline__ int swzA(int u) {
    return u ^ (((u >> 6) & 7) ^ (((u >> 4) & 3) << 1));
}

#define FMA4(A, wv, g) { A.x += wv * fb(g.x); A.y += wv * fb(g.y); A.z += wv * fb(g.z); A.w += wv * fb(g.w); }

// ---------------- CSR hist + W fragment prep (merged) ----------------
__global__ void hist_wprep_kernel(const int* __restrict__ dst, int* __restrict__ cnt,
                                  const float* __restrict__ W1, const float* __restrict__ W2,
                                  unsigned short* __restrict__ W1fh, unsigned short* __restrict__ W1fl,
                                  unsigned short* __restrict__ W2fh, unsigned short* __restrict__ W2fl) {
    int bid = blockIdx.x;
    if (bid < HIST_B) {
        int e = bid * 256 + threadIdx.x;
        if (e < N_EDGES) atomicAdd(&cnt[dst[e]], 1);
        return;
    }
    int s = (bid - HIST_B) * 256 + threadIdx.x;
    if (s < 4096) {
        int lane = s & 63, ks = (s >> 6) & 3, ntile = s >> 8;
        int n = ntile * 16 + (lane & 15);
        int kb = ks * 32 + (lane >> 4) * 8;
#pragma unroll
        for (int j = 0; j < 8; ++j) {
            float w = W1[(kb + j) * L1_OUT + n];
            unsigned short h = bfh(w);
            W1fh[s * 8 + j] = h;
            W1fl[s * 8 + j] = bfh(w - fb(h));
        }
    } else if (s < 6144) {
        int s2 = s - 4096;
        int lane = s2 & 63, ks = (s2 >> 6) & 7, ntile = s2 >> 9;
        int n = ntile * 16 + (lane & 15);
        int kb = ks * 32 + (lane >> 4) * 8;
#pragma unroll
        for (int j = 0; j < 8; ++j) {
            float w = W2[(kb + j) * OUT_DIM + n];
            unsigned short h = bfh(w);
            W2fh[s2 * 8 + j] = h;
            W2fl[s2 * 8 + j] = bfh(w - fb(h));
        }
    }
}

__global__ void scanA_kernel(const int* __restrict__ cnt, int* __restrict__ texcl,
                             int* __restrict__ bsum) {
    __shared__ int sh[SCAN_B];
    int tid = threadIdx.x;
    int i = blockIdx.x * SCAN_B + tid;
    int v = (i < N_NODES) ? cnt[i] : 0;
    sh[tid] = v;
    __syncthreads();
    for (int off = 1; off < SCAN_B; off <<= 1) {
        int t = (tid >= off) ? sh[tid - off] : 0;
        __syncthreads();
        sh[tid] += t;
        __syncthreads();
    }
    if (i < N_NODES) texcl[i] = sh[tid] - v;
    if (tid == SCAN_B - 1) bsum[blockIdx.x] = sh[tid];
}

// merged scanB+scanC: block b reduces its own prefix of bsum, then writes row
__global__ void scanC_kernel(const int* __restrict__ texcl, const int* __restrict__ bsum,
                             int* __restrict__ row, int nb) {
    __shared__ int sh[SCAN_B];
    int b = blockIdx.x;
    int tid = threadIdx.x;
    sh[tid] = (tid < b && tid < nb) ? bsum[tid] : 0;
    __syncthreads();
#pragma unroll
    for (int off = 128; off > 0; off >>= 1) {
        if (tid < off) sh[tid] += sh[tid + off];
        __syncthreads();
    }
    int prefix = sh[0];
    int i = b * SCAN_B + tid;
    if (i < N_NODES) row[i] = texcl[i] + prefix;
    if (b == 0 && tid == 0) row[N_NODES] = N_EDGES;
}

__global__ void fill_kernel(const int* __restrict__ src, const int* __restrict__ dst,
                            const int* __restrict__ row, int* __restrict__ fc,
                            int* __restrict__ perm_src) {
    int e = blockIdx.x * blockDim.x + threadIdx.x;
    if (e >= N_EDGES) return;
    int d = dst[e];
    int p = row[d] + atomicAdd(&fc[d], 1);
    perm_src[p] = src[e];
}

// ---------------- gemm1 (MFMA): feat1b = bf16(X @ W1) + fused el1/er1 ----------------
__global__ __launch_bounds__(512) void gemm1_kernel(const float* __restrict__ X,
                                                    const unsigned short* __restrict__ W1fh,
                                                    const unsigned short* __restrict__ W1fl,
                                                    const float* __restrict__ al1,
                                                    const float* __restrict__ ar1,
                                                    unsigned short* __restrict__ feat1b,
                                                    float* __restrict__ el1,
                                                    float* __restrict__ er1) {
    __shared__ unsigned short Ah[4 * 4 * 64 * 8];   // [mfrag][kstep][lane][j] 16 KB
    int t = threadIdx.x;
    int m0 = blockIdx.x * 64;

    {
        int m = t >> 3;
        int k0 = (t & 7) * 16;
        int mfrag = m >> 4, mrow = m & 15;
        bool valid = (m0 + m) < N_NODES;
        const float4* xr = (const float4*)&X[(size_t)(m0 + m) * IN_DIM];
#pragma unroll
        for (int g = 0; g < 4; ++g) {
            int k = k0 + g * 4;
            float4 v = valid ? xr[k >> 2] : float4{0.f, 0.f, 0.f, 0.f};
            int kstep = k >> 5, kk = k & 31;
            int lane = mrow + 16 * (kk >> 3);
            int j0 = kk & 7;
            int base = ((mfrag * 4 + kstep) * 64 + lane) * 8 + j0;
            *(ushort4*)&Ah[base] = make_ushort4(bfh(v.x), bfh(v.y), bfh(v.z), bfh(v.w));
        }
    }
    __syncthreads();

    int w = t >> 6, lane = t & 63;
    int wr = w >> 2, wc = w & 3;   // wave tile: rows wr*32..+31, cols wc*64..+63 (head wc)
    f32x4 acc[2][4];
#pragma unroll
    for (int mi = 0; mi < 2; ++mi)
#pragma unroll
        for (int nf = 0; nf < 4; ++nf) acc[mi][nf] = f32x4{0.f, 0.f, 0.f, 0.f};

#pragma unroll
    for (int kstep = 0; kstep < 4; ++kstep) {
        bf16x8 a_h[2];
#pragma unroll
        for (int mi = 0; mi < 2; ++mi) {
            int slot = (((wr * 2 + mi) * 4 + kstep) * 64 + lane) * 8;
            a_h[mi] = *(const bf16x8*)&Ah[slot];
        }
#pragma unroll
        for (int nf = 0; nf < 4; ++nf) {
            int slot = (((wc * 4 + nf) * 4 + kstep) * 64 + lane) * 8;
            bf16x8 b_h = *(const bf16x8*)&W1fh[slot];
            bf16x8 b_l = *(const bf16x8*)&W1fl[slot];
#pragma unroll
            for (int mi = 0; mi < 2; ++mi) {
                acc[mi][nf] = __builtin_amdgcn_mfma_f32_16x16x32_bf16(a_h[mi], b_h, acc[mi][nf], 0, 0, 0);
                acc[mi][nf] = __builtin_amdgcn_mfma_f32_16x16x32_bf16(a_h[mi], b_l, acc[mi][nf], 0, 0, 0);
            }
        }
    }

    int fq = lane >> 4, fr = lane & 15;
#pragma unroll
    for (int mi = 0; mi < 2; ++mi) {
#pragma unroll
        for (int j = 0; j < 4; ++j) {
            int r = m0 + wr * 32 + mi * 16 + fq * 4 + j;
            if (r >= N_NODES) continue;
#pragma unroll
            for (int nf = 0; nf < 4; ++nf) {
                int c = wc * 64 + nf * 16 + fr;
                feat1b[(size_t)r * L1_OUT + c] = bfh(acc[mi][nf][j]);
            }
        }
    }

    float al_v[4], ar_v[4];
#pragma unroll
    for (int nf = 0; nf < 4; ++nf) {
        al_v[nf] = al1[wc * 64 + nf * 16 + fr];
        ar_v[nf] = ar1[wc * 64 + nf * 16 + fr];
    }
#pragma unroll
    for (int mi = 0; mi < 2; ++mi) {
#pragma unroll
        for (int j = 0; j < 4; ++j) {
            float l = 0.f, r = 0.f;
#pragma unroll
            for (int nf = 0; nf < 4; ++nf) {
                l += acc[mi][nf][j] * al_v[nf];
                r += acc[mi][nf][j] * ar_v[nf];
            }
#pragma unroll
            for (int off = 1; off < 16; off <<= 1) {
                l += __shfl_xor(l, off, 64);
                r += __shfl_xor(r, off, 64);
            }
            int rr = m0 + wr * 32 + mi * 16 + fq * 4 + j;
            if (fr == 0 && rr < N_NODES) {
                el1[rr * HEADS + wc] = l;
                er1[rr * HEADS + wc] = r;
            }
        }
    }
}

// ---------------- layer2 fused: gather1 (into LDS A-frags, hi-only) + gemm2 MFMA + el2/er2 ----------------
// Block = 512 threads = 8 waves, owns 32 consecutive dsts (4 iterations x 8 waves, sequential).
// Fast-path aggregation uses an 8-deep load batch (single dst stream; r8's regression was
// the cross-dst pairing, not the unroll depth).
__global__ __launch_bounds__(512, 8) void layer2_kernel(const int* __restrict__ row,
                                                        const int* __restrict__ perm_src,
                                                        const float* __restrict__ el1,
                                                        const float* __restrict__ er1,
                                                        const unsigned short* __restrict__ feat1b,
                                                        const float* __restrict__ b1,
                                                        const unsigned short* __restrict__ W2fh,
                                                        const unsigned short* __restrict__ W2fl,
                                                        const float* __restrict__ al2,
                                                        const float* __restrict__ ar2,
                                                        unsigned short* __restrict__ feat2b,
                                                        float* __restrict__ el2,
                                                        float* __restrict__ er2) {
    __shared__ unsigned short Ah[2 * 8 * 64 * 8];   // 16 KB (swizzled slots), hi-only A
    __shared__ float pl[2][4][16], pr[2][4][16];    // [mi][ntile][row]
    int t = threadIdx.x;
    int w = t >> 6, lane = t & 63;
    int n0 = blockIdx.x * 32;

    float4 b1v = *(const float4*)&b1[lane * 4];   // channels lane*4..+3
    const ushort4* f4 = (const ushort4*)feat1b;

    // ---- phase 1: aggregate 32 dst rows into LDS A-fragments (sequential) ----
#pragma unroll 1
    for (int it = 0; it < 4; ++it) {
        int d = n0 + it * 8 + w;
        float4 acc = {0.f, 0.f, 0.f, 0.f};
        bool valid = d < N_NODES;
        if (valid) {
            int base = row[d], deg = row[d + 1] - base;
            if (deg > 0 && deg <= 16) {
                // register softmax: 16-lane group per head, lane jj = edge jj
                int h = lane >> 4, jj = lane & 15;
                int s_reg = (jj < deg) ? perm_src[base + jj] : 0;
                float er_d = er1[d * HEADS + h];
                float sc = (jj < deg) ? leaky(el1[s_reg * HEADS + h] + er_d) : -1e30f;
                float m = sc;
                m = fmaxf(m, __shfl_xor(m, 1, 64));
                m = fmaxf(m, __shfl_xor(m, 2, 64));
                m = fmaxf(m, __shfl_xor(m, 4, 64));
                m = fmaxf(m, __shfl_xor(m, 8, 64));
                float ex = (jj < deg) ? __expf(sc - m) : 0.f;
                float ss = ex;
                ss += __shfl_xor(ss, 1, 64);
                ss += __shfl_xor(ss, 2, 64);
                ss += __shfl_xor(ss, 4, 64);
                ss += __shfl_xor(ss, 8, 64);
                float alpha = ex / ss;
                int hb = lane & 48;
                float4 A0 = {0.f,0.f,0.f,0.f}, A1 = {0.f,0.f,0.f,0.f};
                float4 A2 = {0.f,0.f,0.f,0.f}, A3 = {0.f,0.f,0.f,0.f};
                int j = 0;
                // 8-deep batch: all 8 row loads issue before any FMA consumes them
                for (; j + 7 < deg; j += 8) {
                    int s0 = __shfl(s_reg, j),     s1 = __shfl(s_reg, j + 1);
                    int s2 = __shfl(s_reg, j + 2), s3 = __shfl(s_reg, j + 3);
                    int s4 = __shfl(s_reg, j + 4), s5 = __shfl(s_reg, j + 5);
                    int s6 = __shfl(s_reg, j + 6), s7 = __shfl(s_reg, j + 7);
                    float a0 = __shfl(alpha, hb + j),     a1 = __shfl(alpha, hb + j + 1);
                    float a2 = __shfl(alpha, hb + j + 2), a3 = __shfl(alpha, hb + j + 3);
                    float a4 = __shfl(alpha, hb + j + 4), a5 = __shfl(alpha, hb + j + 5);
                    float a6 = __shfl(alpha, hb + j + 6), a7 = __shfl(alpha, hb + j + 7);
                    ushort4 f0 = f4[(size_t)s0 * 64 + lane];
                    ushort4 f1 = f4[(size_t)s1 * 64 + lane];
                    ushort4 f2 = f4[(size_t)s2 * 64 + lane];
                    ushort4 f3 = f4[(size_t)s3 * 64 + lane];
                    ushort4 f5v = f4[(size_t)s4 * 64 + lane];
                    ushort4 f6v = f4[(size_t)s5 * 64 + lane];
                    ushort4 f7v = f4[(size_t)s6 * 64 + lane];
                    ushort4 f8v = f4[(size_t)s7 * 64 + lane];
                    FMA4(A0, a0, f0);  FMA4(A1, a1, f1);  FMA4(A2, a2, f2);  FMA4(A3, a3, f3);
                    FMA4(A0, a4, f5v); FMA4(A1, a5, f6v); FMA4(A2, a6, f7v); FMA4(A3, a7, f8v);
                }
                for (; j + 3 < deg; j += 4) {
                    int s0 = __shfl(s_reg, j), s1 = __shfl(s_reg, j + 1);
                    int s2 = __shfl(s_reg, j + 2), s3 = __shfl(s_reg, j + 3);
                    float a0 = __shfl(alpha, hb + j), a1 = __shfl(alpha, hb + j + 1);
                    float a2 = __shfl(alpha, hb + j + 2), a3 = __shfl(alpha, hb + j + 3);
                    ushort4 f0 = f4[(size_t)s0 * 64 + lane];
                    ushort4 f1 = f4[(size_t)s1 * 64 + lane];
                    ushort4 f2 = f4[(size_t)s2 * 64 + lane];
                    ushort4 f3 = f4[(size_t)s3 * 64 + lane];
                    FMA4(A0, a0, f0); FMA4(A1, a1, f1); FMA4(A2, a2, f2); FMA4(A3, a3, f3);
                }
                for (; j < deg; ++j) {
                    int s0 = __shfl(s_reg, j);
                    float a0 = __shfl(alpha, hb + j);
                    ushort4 f0 = f4[(size_t)s0 * 64 + lane];
                    FMA4(A0, a0, f0);
                }
                acc.x = A0.x + A1.x + A2.x + A3.x;
                acc.y = A0.y + A1.y + A2.y + A3.y;
                acc.z = A0.z + A1.z + A2.z + A3.z;
                acc.w = A0.w + A1.w + A2.w + A3.w;
            } else if (deg > 16) {
                // rare fallback: strided per-head stats, serial recompute aggregation
                float mh0, mh1, mh2, mh3, iv0, iv1, iv2, iv3;
#pragma unroll
                for (int h = 0; h < 4; ++h) {
                    float er_dh = er1[d * HEADS + h];
                    float m = -1e30f;
                    for (int j = lane; j < deg; j += 64)
                        m = fmaxf(m, leaky(el1[perm_src[base + j] * HEADS + h] + er_dh));
#pragma unroll
                    for (int off = 1; off < 64; off <<= 1) m = fmaxf(m, __shfl_xor(m, off, 64));
                    float ss = 0.f;
                    for (int j = lane; j < deg; j += 64)
                        ss += __expf(leaky(el1[perm_src[base + j] * HEADS + h] + er_dh) - m);
#pragma unroll
                    for (int off = 1; off < 64; off <<= 1) ss += __shfl_xor(ss, off, 64);
                    float iv = 1.f / ss;
                    if (h == 0) { mh0 = m; iv0 = iv; }
                    else if (h == 1) { mh1 = m; iv1 = iv; }
                    else if (h == 2) { mh2 = m; iv2 = iv; }
                    else { mh3 = m; iv3 = iv; }
                }
                int hh = lane >> 4;
                float m_s = hh == 0 ? mh0 : hh == 1 ? mh1 : hh == 2 ? mh2 : mh3;
                float iv_s = hh == 0 ? iv0 : hh == 1 ? iv1 : hh == 2 ? iv2 : iv3;
                float er_s = er1[d * HEADS + hh];
                for (int j = 0; j < deg; ++j) {
                    int s = perm_src[base + j];
                    float a = __expf(leaky(el1[s * HEADS + hh] + er_s) - m_s) * iv_s;
                    ushort4 f0 = f4[(size_t)s * 64 + lane];
                    FMA4(acc, a, f0);
                }
            }
            // deg==0: acc stays 0
            acc.x += b1v.x; acc.y += b1v.y; acc.z += b1v.z; acc.w += b1v.w;
        }
        // write row m = it*8+w, channels lane*4..+3 into swizzled A-frag layout (hi only)
        int m = it * 8 + w;
        int mfrag = m >> 4, mrow = m & 15;
        int c = lane * 4;
        int kstep = c >> 5;
        int g = (c & 31) >> 3;
        int u = (mfrag * 8 + kstep) * 64 + mrow + 16 * g;
        int basei = swzA(u) * 8 + (c & 7);
        *(ushort4*)&Ah[basei] = make_ushort4(bfh(acc.x), bfh(acc.y), bfh(acc.z), bfh(acc.w));
    }
    __syncthreads();

    // ---- phase 2: gemm2 MFMA; wave = (mi, ntile), 16x16 output each ----
    int mi = w & 1, ntile = w >> 1;
    f32x4 acc2 = f32x4{0.f, 0.f, 0.f, 0.f};

#pragma unroll
    for (int ks = 0; ks < 8; ++ks) {
        int aslot = swzA((mi * 8 + ks) * 64 + lane) * 8;
        bf16x8 a_h = *(const bf16x8*)&Ah[aslot];
        int slot = ((ntile * 8 + ks) * 64 + lane) * 8;
        bf16x8 b_h = *(const bf16x8*)&W2fh[slot];
        bf16x8 b_l = *(const bf16x8*)&W2fl[slot];
        acc2 = __builtin_amdgcn_mfma_f32_16x16x32_bf16(a_h, b_h, acc2, 0, 0, 0);
        acc2 = __builtin_amdgcn_mfma_f32_16x16x32_bf16(a_h, b_l, acc2, 0, 0, 0);
    }

    int fq = lane >> 4, fr = lane & 15;
#pragma unroll
    for (int j = 0; j < 4; ++j) {
        int r = n0 + mi * 16 + fq * 4 + j;
        if (r < N_NODES) {
            int c = ntile * 16 + fr;
            feat2b[(size_t)r * OUT_DIM + c] = bfh(acc2[j]);
        }
    }

    // fused el2/er2: per-wave partial over 16 cols, combine 4 ntiles in LDS
    float al_v = al2[ntile * 16 + fr];
    float ar_v = ar2[ntile * 16 + fr];
#pragma unroll
    for (int j = 0; j < 4; ++j) {
        float l = acc2[j] * al_v;
        float r = acc2[j] * ar_v;
#pragma unroll
        for (int off = 1; off < 16; off <<= 1) {
            l += __shfl_xor(l, off, 64);
            r += __shfl_xor(r, off, 64);
        }
        if (fr == 0) {
            pl[mi][ntile][fq * 4 + j] = l;
            pr[mi][ntile][fq * 4 + j] = r;
        }
    }
    __syncthreads();
    if (t < 32) {
        int n = n0 + t;
        if (n < N_NODES) {
            int mi2 = t >> 4, rr = t & 15;
            el2[n] = pl[mi2][0][rr] + pl[mi2][1][rr] + pl[mi2][2][rr] + pl[mi2][3][rr];
            er2[n] = pr[mi2][0][rr] + pr[mi2][1][rr] + pr[mi2][2][rr] + pr[mi2][3][rr];
        }
    }
}

// ---------------- gather2: register softmax + aggregate + bias, 4 dsts/block, no LDS ----------------
__global__ __launch_bounds__(256) void gather2_kernel(const int* __restrict__ row,
                                                      const int* __restrict__ perm_src,
                                                      const float* __restrict__ el2,
                                                      const float* __restrict__ er2,
                                                      const unsigned short* __restrict__ feat2b,
                                                      const float* __restrict__ b2,
                                                      float* __restrict__ out) {
    int tid = threadIdx.x;
    int w = tid >> 6, lane = tid & 63;
    int d = blockIdx.x * 4 + w;
    int base = row[d], deg = row[d + 1] - base;
    float bias = b2[lane];
    if (deg == 0) {
        out[(size_t)d * OUT_DIM + lane] = bias;
        return;
    }
    if (deg <= 64) {
        int s_reg = (lane < deg) ? perm_src[base + lane] : 0;
        float er_d = er2[d];
        float sc = (lane < deg) ? leaky(el2[s_reg] + er_d) : -1e30f;
        float m = sc;
#pragma unroll
        for (int off = 1; off < 64; off <<= 1) m = fmaxf(m, __shfl_xor(m, off, 64));
        float ex = (lane < deg) ? __expf(sc - m) : 0.f;
        float ss = ex;
#pragma unroll
        for (int off = 1; off < 64; off <<= 1) ss += __shfl_xor(ss, off, 64);
        float alpha = ex / ss;
        float a0 = 0.f, a1 = 0.f, a2 = 0.f, a3 = 0.f;
        float a4 = 0.f, a5 = 0.f, a6 = 0.f, a7 = 0.f;
        int j = 0;
        for (; j + 7 < deg; j += 8) {
            int s0 = __shfl(s_reg, j),     s1 = __shfl(s_reg, j + 1);
            int s2 = __shfl(s_reg, j + 2), s3 = __shfl(s_reg, j + 3);
            int s4 = __shfl(s_reg, j + 4), s5 = __shfl(s_reg, j + 5);
            int s6 = __shfl(s_reg, j + 6), s7 = __shfl(s_reg, j + 7);
            float w0 = __shfl(alpha, j),     w1 = __shfl(alpha, j + 1);
            float w2 = __shfl(alpha, j + 2), w3 = __shfl(alpha, j + 3);
            float w4 = __shfl(alpha, j + 4), w5 = __shfl(alpha, j + 5);
            float w6 = __shfl(alpha, j + 6), w7 = __shfl(alpha, j + 7);
            a0 += w0 * fb(feat2b[(size_t)s0 * OUT_DIM + lane]);
            a1 += w1 * fb(feat2b[(size_t)s1 * OUT_DIM + lane]);
            a2 += w2 * fb(feat2b[(size_t)s2 * OUT_DIM + lane]);
            a3 += w3 * fb(feat2b[(size_t)s3 * OUT_DIM + lane]);
            a4 += w4 * fb(feat2b[(size_t)s4 * OUT_DIM + lane]);
            a5 += w5 * fb(feat2b[(size_t)s5 * OUT_DIM + lane]);
            a6 += w6 * fb(feat2b[(size_t)s6 * OUT_DIM + lane]);
            a7 += w7 * fb(feat2b[(size_t)s7 * OUT_DIM + lane]);
        }
        for (; j + 3 < deg; j += 4) {
            int s0 = __shfl(s_reg, j),     s1 = __shfl(s_reg, j + 1);
            int s2 = __shfl(s_reg, j + 2), s3 = __shfl(s_reg, j + 3);
            float w0 = __shfl(alpha, j),     w1 = __shfl(alpha, j + 1);
            float w2 = __shfl(alpha, j + 2), w3 = __shfl(alpha, j + 3);
            a0 += w0 * fb(feat2b[(size_t)s0 * OUT_DIM + lane]);
            a1 += w1 * fb(feat2b[(size_t)s1 * OUT_DIM + lane]);
            a2 += w2 * fb(feat2b[(size_t)s2 * OUT_DIM + lane]);
            a3 += w3 * fb(feat2b[(size_t)s3 * OUT_DIM + lane]);
        }
        for (; j < deg; ++j) {
            int s0 = __shfl(s_reg, j);
            float w0 = __shfl(alpha, j);
            a0 += w0 * fb(feat2b[(size_t)s0 * OUT_DIM + lane]);
        }
        out[(size_t)d * OUT_DIM + lane] = a0 + a1 + a2 + a3 + a4 + a5 + a6 + a7 + bias;
    } else {
        // rare fallback deg > 64: recompute path
        float er_d = er2[d];
        float m = -1e30f;
        for (int j = lane; j < deg; j += 64)
            m = fmaxf(m, leaky(el2[perm_src[base + j]] + er_d));
#pragma unroll
        for (int off = 1; off < 64; off <<= 1) m = fmaxf(m, __shfl_xor(m, off, 64));
        float ss = 0.f;
        for (int j = lane; j < deg; j += 64)
            ss += __expf(leaky(el2[perm_src[base + j]] + er_d) - m);
#pragma unroll
        for (int off = 1; off < 64; off <<= 1) ss += __shfl_xor(ss, off, 64);
        float inv = 1.f / ss;
        float a0 = 0.f;
        for (int j = 0; j < deg; ++j) {
            int s = perm_src[base + j];
            float a = __expf(leaky(el2[s] + er_d) - m) * inv;
            a0 += a * fb(feat2b[(size_t)s * OUT_DIM + lane]);
        }
        out[(size_t)d * OUT_DIM + lane] = a0 + bias;
    }
}

extern "C" void kernel_launch(void* const* d_in, const int* in_sizes, int n_in,
                              void* d_out, int out_size, void* d_ws, size_t ws_size,
                              hipStream_t stream) {
    const float* features = (const float*)d_in[0];
    const int* src = (const int*)d_in[1];
    const int* dst = (const int*)d_in[2];
    const float* W1 = (const float*)d_in[3];
    const float* al1 = (const float*)d_in[4];
    const float* ar1 = (const float*)d_in[5];
    const float* b1 = (const float*)d_in[6];
    const float* W2 = (const float*)d_in[7];
    const float* al2 = (const float*)d_in[8];
    const float* ar2 = (const float*)d_in[9];
    const float* b2 = (const float*)d_in[10];
    float* out = (float*)d_out;

    // workspace layout
    float* ws = (float*)d_ws;
    float* el1 = ws;                                           // N*4
    float* er1 = el1 + N_NODES * HEADS;                        // N*4
    float* el2 = er1 + N_NODES * HEADS;                        // N
    float* er2 = el2 + N_NODES;                                // N
    unsigned short* feat1b = (unsigned short*)(er2 + N_NODES); // N*256 bf16
    unsigned short* feat2b = feat1b + (size_t)N_NODES * L1_OUT;// N*64 bf16
    unsigned short* W1fh = feat2b + (size_t)N_NODES * OUT_DIM; // 32768
    unsigned short* W1fl = W1fh + 32768;                       // 32768
    unsigned short* W2fh = W1fl + 32768;                       // 16384
    unsigned short* W2fl = W2fh + 16384;                       // 16384
    int* cnt = (int*)(W2fl + 16384);                           // N
    int* fc = cnt + N_NODES;                                   // N
    int* texcl = fc + N_NODES;                                 // N
    int* bsum = texcl + N_NODES;                               // 256
    int* row = bsum + 256;                                     // N+1
    int* perm_src = row + N_NODES + 1;                         // E

    const int nscan = (N_NODES + SCAN_B - 1) / SCAN_B;   // 196

    hipMemsetAsync(cnt, 0, (size_t)2 * N_NODES * sizeof(int), stream);  // cnt + fc

    // CSR build + weight prep
    hist_wprep_kernel<<<HIST_B + 24, 256, 0, stream>>>(dst, cnt, W1, W2, W1fh, W1fl, W2fh, W2fl);
    scanA_kernel<<<nscan, SCAN_B, 0, stream>>>(cnt, texcl, bsum);
    scanC_kernel<<<nscan, SCAN_B, 0, stream>>>(texcl, bsum, row, nscan);
    fill_kernel<<<(N_EDGES + 255) / 256, 256, 0, stream>>>(src, dst, row, fc, perm_src);

    // layer 1 GEMM (+el1/er1)
    gemm1_kernel<<<(N_NODES + 63) / 64, 512, 0, stream>>>(features, W1fh, W1fl, al1, ar1,
                                                          feat1b, el1, er1);
    // layer 1 gather fused with layer 2 GEMM (+el2/er2)
    layer2_kernel<<<(N_NODES + 31) / 32, 512, 0, stream>>>(row, perm_src, el1, er1, feat1b,
                                                           b1, W2fh, W2fl, al2, ar2,
                                                           feat2b, el2, er2);
    // layer 2 gather (+bias)
    gather2_kernel<<<N_NODES / 4, 256, 0, stream>>>(row, perm_src, el2, er2, feat2b, b2, out);
}